// Round 5
// baseline (267.204 us; speedup 1.0000x reference)
//
#include <hip/hip_runtime.h>
#include <math.h>

#define NBATCH 4096
#define TNUM   128
#define NOBSC  10
#define MAXIT  30

// ws layout (floats)
#define WS_MX   0      // 16x16
#define WS_MY   256    // 16x16
#define WS_MGX  512    // 16x16  (Mx*Gx)
#define WS_MGY  768    // 16x16  (My*Gy)
#define WS_NX   1024   // 16x8
#define WS_NY   1152   // 16x9
#define WS_NX0  1296   // 16x8
#define WS_NY0  1424   // 16x9
// total 1568 floats

#define RSTRIDE 132    // padded row stride for reduction buffer (33 x 16B)

union F4 { float4 v; float f[4]; };

__device__ __forceinline__ float rl(float v, int k) {
  return __int_as_float(__builtin_amdgcn_readlane(__float_as_int(v), k));
}

// ---------------- setup kernel: build + invert KKT matrices (fp64 GJ) -------
__global__ __launch_bounds__(64) void planner_setup(
    const float* __restrict__ P, const float* __restrict__ Pd, const float* __restrict__ Pdd,
    float* __restrict__ ws)
{
  const int mid = blockIdx.x;   // 0: (cost_sm,Ax)->Nx0  1: (cost_sm,Ay)->Ny0
                                // 2: (cost_x,Ax)->Mx,Nx,MGx 3: (cost_y,Ay)->My,Ny,MGy
  const int tid = threadIdx.x;
  __shared__ double C[16][16];
  __shared__ double G[16][16];
  __shared__ double Ae[9][16];
  __shared__ double aug[25][50];
  __shared__ int pivs;

  const bool isY = (mid & 1);
  const int  m   = isY ? 9 : 8;
  const int  n   = 16 + m;
  const int  w   = 2 * n;

  // Gram matrices + cost matrix
  for (int e = tid; e < 256; e += 64) {
    const int j = e >> 4, k = e & 15;
    double gdd = 0.0, gd = 0.0, g0 = 0.0;
    for (int t = 0; t < TNUM; ++t) {
      gdd += (double)Pdd[t*16+j] * (double)Pdd[t*16+k];
      gd  += (double)Pd [t*16+j] * (double)Pd [t*16+k];
      g0  += (double)P  [t*16+j] * (double)P  [t*16+k];
    }
    const double cs = 100.0 * (gdd + ((j == k) ? 0.1 : 0.0));   // cost_sm
    const double g  = gdd + gd + (isY ? 12.0 : 10.0) * g0;      // Gx or Gy
    G[j][k] = g;
    C[j][k] = (mid >= 2) ? (cs + g) : cs;
  }
  if (tid < 16) {
    const int j = tid;
    Ae[0][j] = (double)P  [0*16+j];
    Ae[1][j] = (double)Pd [0*16+j];
    Ae[2][j] = (double)Pdd[0*16+j];
    if (!isY) {
      Ae[3][j] = (double)Pd[127*16+j];
      for (int r = 4; r < 8; ++r) Ae[r][j] = (j == r) ? 1.0 : 0.0;
    } else {
      Ae[3][j] = (double)P [127*16+j];
      Ae[4][j] = (double)Pd[127*16+j];
      for (int r = 5; r < 9; ++r) Ae[r][j] = (j == (r-1)) ? 1.0 : 0.0;
    }
  }
  __syncthreads();

  // build augmented [KKT | I]
  for (int e = tid; e < n * w; e += 64) {
    const int r = e / w, c = e % w;
    double val;
    if (c < n) {
      if (r < 16) val = (c < 16) ? C[r][c] : Ae[c-16][r];
      else        val = (c < 16) ? Ae[r-16][c] : 0.0;
    } else {
      val = ((c - n) == r) ? 1.0 : 0.0;
    }
    aug[r][c] = val;
  }
  __syncthreads();

  // Gauss-Jordan with partial pivoting
  for (int k = 0; k < n; ++k) {
    if (tid == 0) {
      int p = k; double best = fabs(aug[k][k]);
      for (int r = k+1; r < n; ++r) { double a = fabs(aug[r][k]); if (a > best) { best = a; p = r; } }
      pivs = p;
    }
    __syncthreads();
    const int p = pivs;
    if (p != k) {
      for (int c = tid; c < w; c += 64) { double t = aug[k][c]; aug[k][c] = aug[p][c]; aug[p][c] = t; }
    }
    __syncthreads();
    const double ipiv = 1.0 / aug[k][k];
    for (int c = tid; c < w; c += 64) aug[k][c] *= ipiv;
    __syncthreads();
    for (int r = tid; r < n; r += 64) {
      if (r != k) {
        const double f = aug[r][k];
        for (int c = k; c < w; ++c) aug[r][c] -= f * aug[k][c];
      }
    }
    __syncthreads();
  }

  // write sub-blocks of the inverse (cols n.. of aug)
  if (mid == 0) {
    for (int e = tid; e < 16*8; e += 64) ws[WS_NX0 + e] = (float)aug[e >> 3][n + 16 + (e & 7)];
  } else if (mid == 1) {
    for (int e = tid; e < 16*9; e += 64) ws[WS_NY0 + e] = (float)aug[e / 9][n + 16 + (e % 9)];
  } else if (mid == 2) {
    for (int e = tid; e < 256;  e += 64) ws[WS_MX + e] = (float)aug[e >> 4][n + (e & 15)];
    for (int e = tid; e < 16*8; e += 64) ws[WS_NX + e] = (float)aug[e >> 3][n + 16 + (e & 7)];
  } else {
    for (int e = tid; e < 256;  e += 64) ws[WS_MY + e] = (float)aug[e >> 4][n + (e & 15)];
    for (int e = tid; e < 16*9; e += 64) ws[WS_NY + e] = (float)aug[e / 9][n + 16 + (e % 9)];
  }

  // MG = M * G  (fp64), for the fused per-iteration solve
  if (mid >= 2) {
    for (int e = tid; e < 256; e += 64) {
      const int j = e >> 4, k = e & 15;
      double s = 0.0;
      for (int mm = 0; mm < 16; ++mm) s += aug[j][n + mm] * G[mm][k];
      ws[(mid == 2 ? WS_MGX : WS_MGY) + e] = (float)s;
    }
  }
}

// ---------------- main kernel: 128 threads (2 waves) per batch element ------
__global__ __launch_bounds__(128, 2) void planner_main(
    const float* __restrict__ P, const float* __restrict__ Pd, const float* __restrict__ Pdd,
    const float* __restrict__ init_state, const float* __restrict__ fin_state,
    const float* __restrict__ cobs, const float* __restrict__ vobs,
    const float* __restrict__ yub_g, const float* __restrict__ ylb_g,
    const float* __restrict__ lamx_g, const float* __restrict__ lamy_g,
    const float* __restrict__ cxp_g, const float* __restrict__ cyp_g,
    const float* __restrict__ ws, float* __restrict__ out)
{
  const int b    = blockIdx.x;
  const int tid  = threadIdx.x;
  const int lane = tid & 63;
  const int wv   = tid >> 6;
  const int r32  = lane & 31;          // reduction row owned (dup over lane>=32)
  const int rr   = tid & 15;           // solve row
  const int side = (tid >> 4) & 1;     // 0 = x-side, 1 = y-side

  __shared__ alignas(16) float red[32*RSTRIDE];   // padded [o][t]
  __shared__ alignas(16) float cLw[2][32];        // per-wave primal copy (solve only)
  __shared__ alignas(16) float hLw[2][32];        // per-wave h copy (solve only)
  __shared__ float pL[2][32];                     // cross-wave partials

  // basis rows for this lane's timestep t = tid
  float Pr[16], Pdr[16], Pddr[16];
  #pragma unroll
  for (int q = 0; q < 4; ++q) {
    const float4 a  = *reinterpret_cast<const float4*>(P   + tid*16 + 4*q);
    const float4 bb = *reinterpret_cast<const float4*>(Pd  + tid*16 + 4*q);
    const float4 cc = *reinterpret_cast<const float4*>(Pdd + tid*16 + 4*q);
    Pr  [4*q+0]=a.x;  Pr  [4*q+1]=a.y;  Pr  [4*q+2]=a.z;  Pr  [4*q+3]=a.w;
    Pdr [4*q+0]=bb.x; Pdr [4*q+1]=bb.y; Pdr [4*q+2]=bb.z; Pdr [4*q+3]=bb.w;
    Pddr[4*q+0]=cc.x; Pddr[4*q+1]=cc.y; Pddr[4*q+2]=cc.z; Pddr[4*q+3]=cc.w;
  }

  // pre-scaled obstacle trajectories at this timestep
  float xot32[10], yot6[10];
  {
    const float tt = (float)tid * (10.0f/127.0f);
    #pragma unroll
    for (int oo = 0; oo < NOBSC; ++oo) {
      xot32[oo] = 3.2f * fmaf(vobs[b*20+oo],      tt, cobs[b*20+oo]);
      yot6 [oo] = 6.0f * fmaf(vobs[b*20+10+oo],   tt, cobs[b*20+10+oo]);
    }
  }
  const float yub = yub_g[b], ylb = ylb_g[b];

  // solve-row matrices pinned in registers (loaded once, L2-hot)
  float Mreg[16], MGreg[16];
  {
    const float* Mrow  = ws + (side ? WS_MY  : WS_MX ) + rr*16;
    const float* MGrow = ws + (side ? WS_MGY : WS_MGX) + rr*16;
    #pragma unroll
    for (int q = 0; q < 4; ++q) {
      const float4 m4 = *reinterpret_cast<const float4*>(Mrow  + 4*q);
      const float4 g4 = *reinterpret_cast<const float4*>(MGrow + 4*q);
      Mreg [4*q+0]=m4.x; Mreg [4*q+1]=m4.y; Mreg [4*q+2]=m4.z; Mreg [4*q+3]=m4.w;
      MGreg[4*q+0]=g4.x; MGreg[4*q+1]=g4.y; MGreg[4*q+2]=g4.z; MGreg[4*q+3]=g4.w;
    }
  }

  // per-lane solve-row setup: const term, initial c, lambda
  float lam, constv, myc;
  {
    float beq[9];
    const float vi  = init_state[b*4+2];
    const float psi = init_state[b*4+3];
    if (side == 0) {
      beq[0] = init_state[b*4+0];
      beq[1] = vi * cosf(psi);
      beq[2] = 0.f;
      beq[3] = fin_state[b*3+0];
      #pragma unroll
      for (int i2 = 0; i2 < 4; ++i2) beq[4+i2] = cxp_g[b*4+i2];
      beq[8] = 0.f;                      // pad: element 8 multiplies in-bounds junk * 0
    } else {
      beq[0] = init_state[b*4+1];
      beq[1] = vi * sinf(psi);
      beq[2] = 0.f;
      beq[3] = fin_state[b*3+1];
      beq[4] = 0.f;
      #pragma unroll
      for (int i2 = 0; i2 < 4; ++i2) beq[5+i2] = cyp_g[b*4+i2];
    }
    const int nstr = side ? 9 : 8;
    const float* Np  = ws + (side ? WS_NY  : WS_NX ) + rr*nstr;
    const float* N0p = ws + (side ? WS_NY0 : WS_NX0) + rr*nstr;
    float cv = 0.f, c0 = 0.f;
    #pragma unroll
    for (int mm = 0; mm < 9; ++mm) {     // x-side mm=8 reads next row * 0 (in-bounds)
      const float bm = beq[mm];
      cv = fmaf(Np[mm],  bm, cv);
      c0 = fmaf(N0p[mm], bm, c0);
    }
    constv = cv;
    myc    = c0;
    lam = (side == 0) ? lamx_g[b*16 + rr] : lamy_g[b*16 + rr];
    if (lane < 32) cLw[wv][lane] = c0;   // per-wave copy (same-wave DS order)
  }

  #pragma unroll 1
  for (int it = 0; it < MAXIT; ++it) {
    // forward matvec via readlane broadcast of the lane-distributed c
    // (lane k holds cx[k], lane 16+k holds cy[k]; identical in both waves)
    float x=0.f, y=0.f, xd=0.f, yd=0.f, xdd=0.f, ydd=0.f;
    #pragma unroll
    for (int k = 0; k < 16; ++k) {
      const float cxk = rl(myc, k);
      const float cyk = rl(myc, k + 16);
      x   = fmaf(Pr  [k], cxk, x);   y   = fmaf(Pr  [k], cyk, y);
      xd  = fmaf(Pdr [k], cxk, xd);  yd  = fmaf(Pdr [k], cyk, yd);
      xdd = fmaf(Pddr[k], cxk, xdd); ydd = fmaf(Pddr[k], cyk, ydd);
    }

    // projections (residual factors)
    const float ria = rsqrtf(fmaxf(fmaf(xdd, xdd, ydd*ydd), 1e-36f));
    const float ga1 = 1.0f - fminf(1.0f, 18.0f * ria);
    const float riv = rsqrtf(fmaxf(fmaf(xd, xd, yd*yd), 1e-36f));
    const float gv1 = 1.0f - fminf(fmaxf(1.0f, 0.1f*riv), 30.0f*riv);

    // obstacles
    float Sxp = 0.f, Syp = 0.f;
    #pragma unroll
    for (int oo = 0; oo < NOBSC; ++oo) {
      const float bw = fmaf(3.2f, x, -xot32[oo]);
      const float aw = fmaf(6.0f, y, -yot6[oo]);
      const float ri = rsqrtf(fmaxf(fmaf(bw, bw, aw*aw), 1e-36f));
      const float e  = fmaxf(fmaf(19.2f, ri, -1.0f), 0.f);
      Sxp = fmaf(e, bw, Sxp);
      Syp = fmaf(e, aw, Syp);
    }
    const float c0p = -Sxp * 0.3125f;                        // -Sx
    const float rln = fmaxf(y - yub, 0.f) - fmaxf(ylb - y, 0.f);
    const float c2p = rln - Syp * (1.0f/6.0f);               // rln - Sy
    const float c0dd = xdd * ga1, c0d = xd * gv1;
    const float c2dd = ydd * ga1, c2d = yd * gv1;

    // residual back-projection straight into LDS
    {
      float* col = red + tid;
      #pragma unroll
      for (int j = 0; j < 16; ++j) {
        col[j*RSTRIDE]      = fmaf(c0dd, Pddr[j], fmaf(c0d, Pdr[j], c0p * Pr[j]));
        col[(16+j)*RSTRIDE] = fmaf(c2dd, Pddr[j], fmaf(c2d, Pdr[j], c2p * Pr[j]));
      }
    }
    __syncthreads();                                   // A: red ready

    // reduce: lane (r32, qq) sums a 32-col chunk; conflict-free via RSTRIDE
    float h;
    {
      const int qq = tid >> 5;
      const float* rb = red + r32*RSTRIDE + (qq & 1)*32 + wv*64;
      float s0=0.f, s1=0.f, s2=0.f, s3=0.f;
      #pragma unroll
      for (int mch = 0; mch < 8; ++mch) {
        const float4 t = *reinterpret_cast<const float4*>(rb + 4*mch);
        s0 += t.x; s1 += t.y; s2 += t.z; s3 += t.w;
      }
      float s = (s0 + s1) + (s2 + s3);
      s += __shfl_xor(s, 32);                          // wave-local 64-col sum
      if (lane < 32) pL[wv][lane] = s;
      __syncthreads();                                 // B: partials ready

      const float S = s + pL[wv ^ 1][r32];             // full 128-col sum
      lam -= S;
      h = lam - S;                                     // lam_old - 2S
      if (lane < 32) hLw[wv][lane] = h;
    }

    // fused solve: c' = MG*c + M*h + const   (side-sliced reads from per-wave LDS)
    {
      float acc = constv;
      #pragma unroll
      for (int q = 0; q < 4; ++q) {
        F4 h4, c4;
        h4.v = *reinterpret_cast<const float4*>(&hLw[wv][side*16 + 4*q]);
        c4.v = *reinterpret_cast<const float4*>(&cLw[wv][side*16 + 4*q]);
        #pragma unroll
        for (int j = 0; j < 4; ++j)
          acc = fmaf(MGreg[4*q+j], c4.f[j], fmaf(Mreg[4*q+j], h4.f[j], acc));
      }
      myc = acc;
      if (lane < 32) cLw[wv][lane] = acc;              // own wave's copy
    }
  }

  if (tid < 32) out[b*32 + tid] = myc;
}

extern "C" void kernel_launch(void* const* d_in, const int* in_sizes, int n_in,
                              void* d_out, int out_size, void* d_ws, size_t ws_size,
                              hipStream_t stream) {
  const float* P    = (const float*)d_in[0];
  const float* Pd   = (const float*)d_in[1];
  const float* Pdd  = (const float*)d_in[2];
  const float* init = (const float*)d_in[3];
  const float* fin  = (const float*)d_in[4];
  const float* cobs = (const float*)d_in[5];
  const float* vobs = (const float*)d_in[6];
  const float* yub  = (const float*)d_in[7];
  const float* ylb  = (const float*)d_in[8];
  const float* lamx = (const float*)d_in[9];
  const float* lamy = (const float*)d_in[10];
  const float* cxp  = (const float*)d_in[11];
  const float* cyp  = (const float*)d_in[12];
  float* ws  = (float*)d_ws;
  float* o   = (float*)d_out;

  planner_setup<<<dim3(4), dim3(64), 0, stream>>>(P, Pd, Pdd, ws);
  planner_main<<<dim3(NBATCH), dim3(128), 0, stream>>>(
      P, Pd, Pdd, init, fin, cobs, vobs, yub, ylb, lamx, lamy, cxp, cyp, ws, o);
}

// Round 6
// 266.211 us; speedup vs baseline: 1.0037x; 1.0037x over previous
//
#include <hip/hip_runtime.h>
#include <math.h>

#define NBATCH 4096
#define TNUM   128
#define NOBSC  10
#define MAXIT  30

// ws layout (floats)
#define WS_MX   0      // 16x16
#define WS_MY   256    // 16x16
#define WS_MGX  512    // 16x16  (Mx*Gx)
#define WS_MGY  768    // 16x16  (My*Gy)
#define WS_NX   1024   // 16x8
#define WS_NY   1152   // 16x9
#define WS_NX0  1296   // 16x8
#define WS_NY0  1424   // 16x9
// total 1568 floats

#define RSTRIDE 132    // padded row stride for reduction buffer (33 x 16B)

union F4 { float4 v; float f[4]; };

// ---------------- setup kernel: build + invert KKT matrices (fp64 GJ) -------
__global__ __launch_bounds__(64) void planner_setup(
    const float* __restrict__ P, const float* __restrict__ Pd, const float* __restrict__ Pdd,
    float* __restrict__ ws)
{
  const int mid = blockIdx.x;   // 0: (cost_sm,Ax)->Nx0  1: (cost_sm,Ay)->Ny0
                                // 2: (cost_x,Ax)->Mx,Nx,MGx 3: (cost_y,Ay)->My,Ny,MGy
  const int tid = threadIdx.x;
  __shared__ double C[16][16];
  __shared__ double G[16][16];
  __shared__ double Ae[9][16];
  __shared__ double aug[25][50];
  __shared__ int pivs;

  const bool isY = (mid & 1);
  const int  m   = isY ? 9 : 8;
  const int  n   = 16 + m;
  const int  w   = 2 * n;

  // Gram matrices + cost matrix
  for (int e = tid; e < 256; e += 64) {
    const int j = e >> 4, k = e & 15;
    double gdd = 0.0, gd = 0.0, g0 = 0.0;
    for (int t = 0; t < TNUM; ++t) {
      gdd += (double)Pdd[t*16+j] * (double)Pdd[t*16+k];
      gd  += (double)Pd [t*16+j] * (double)Pd [t*16+k];
      g0  += (double)P  [t*16+j] * (double)P  [t*16+k];
    }
    const double cs = 100.0 * (gdd + ((j == k) ? 0.1 : 0.0));   // cost_sm
    const double g  = gdd + gd + (isY ? 12.0 : 10.0) * g0;      // Gx or Gy
    G[j][k] = g;
    C[j][k] = (mid >= 2) ? (cs + g) : cs;
  }
  if (tid < 16) {
    const int j = tid;
    Ae[0][j] = (double)P  [0*16+j];
    Ae[1][j] = (double)Pd [0*16+j];
    Ae[2][j] = (double)Pdd[0*16+j];
    if (!isY) {
      Ae[3][j] = (double)Pd[127*16+j];
      for (int r = 4; r < 8; ++r) Ae[r][j] = (j == r) ? 1.0 : 0.0;
    } else {
      Ae[3][j] = (double)P [127*16+j];
      Ae[4][j] = (double)Pd[127*16+j];
      for (int r = 5; r < 9; ++r) Ae[r][j] = (j == (r-1)) ? 1.0 : 0.0;
    }
  }
  __syncthreads();

  // build augmented [KKT | I]
  for (int e = tid; e < n * w; e += 64) {
    const int r = e / w, c = e % w;
    double val;
    if (c < n) {
      if (r < 16) val = (c < 16) ? C[r][c] : Ae[c-16][r];
      else        val = (c < 16) ? Ae[r-16][c] : 0.0;
    } else {
      val = ((c - n) == r) ? 1.0 : 0.0;
    }
    aug[r][c] = val;
  }
  __syncthreads();

  // Gauss-Jordan with partial pivoting
  for (int k = 0; k < n; ++k) {
    if (tid == 0) {
      int p = k; double best = fabs(aug[k][k]);
      for (int r = k+1; r < n; ++r) { double a = fabs(aug[r][k]); if (a > best) { best = a; p = r; } }
      pivs = p;
    }
    __syncthreads();
    const int p = pivs;
    if (p != k) {
      for (int c = tid; c < w; c += 64) { double t = aug[k][c]; aug[k][c] = aug[p][c]; aug[p][c] = t; }
    }
    __syncthreads();
    const double ipiv = 1.0 / aug[k][k];
    for (int c = tid; c < w; c += 64) aug[k][c] *= ipiv;
    __syncthreads();
    for (int r = tid; r < n; r += 64) {
      if (r != k) {
        const double f = aug[r][k];
        for (int c = k; c < w; ++c) aug[r][c] -= f * aug[k][c];
      }
    }
    __syncthreads();
  }

  // write sub-blocks of the inverse (cols n.. of aug)
  if (mid == 0) {
    for (int e = tid; e < 16*8; e += 64) ws[WS_NX0 + e] = (float)aug[e >> 3][n + 16 + (e & 7)];
  } else if (mid == 1) {
    for (int e = tid; e < 16*9; e += 64) ws[WS_NY0 + e] = (float)aug[e / 9][n + 16 + (e % 9)];
  } else if (mid == 2) {
    for (int e = tid; e < 256;  e += 64) ws[WS_MX + e] = (float)aug[e >> 4][n + (e & 15)];
    for (int e = tid; e < 16*8; e += 64) ws[WS_NX + e] = (float)aug[e >> 3][n + 16 + (e & 7)];
  } else {
    for (int e = tid; e < 256;  e += 64) ws[WS_MY + e] = (float)aug[e >> 4][n + (e & 15)];
    for (int e = tid; e < 16*9; e += 64) ws[WS_NY + e] = (float)aug[e / 9][n + 16 + (e % 9)];
  }

  // MG = M * G  (fp64), for the fused per-iteration solve
  if (mid >= 2) {
    for (int e = tid; e < 256; e += 64) {
      const int j = e >> 4, k = e & 15;
      double s = 0.0;
      for (int mm = 0; mm < 16; ++mm) s += aug[j][n + mm] * G[mm][k];
      ws[(mid == 2 ? WS_MGX : WS_MGY) + e] = (float)s;
    }
  }
}

// ---------------- main kernel: 128 threads (2 waves) per batch element ------
__global__ __launch_bounds__(128) void planner_main(
    const float* __restrict__ P, const float* __restrict__ Pd, const float* __restrict__ Pdd,
    const float* __restrict__ init_state, const float* __restrict__ fin_state,
    const float* __restrict__ cobs, const float* __restrict__ vobs,
    const float* __restrict__ yub_g, const float* __restrict__ ylb_g,
    const float* __restrict__ lamx_g, const float* __restrict__ lamy_g,
    const float* __restrict__ cxp_g, const float* __restrict__ cyp_g,
    const float* __restrict__ ws, float* __restrict__ out)
{
  const int b    = blockIdx.x;
  const int tid  = threadIdx.x;
  const int lane = tid & 63;
  const int wv   = tid >> 6;
  const int r16  = lane & 15;          // reduction row owned
  const int rr   = tid & 15;           // solve row
  const int side = (tid >> 4) & 1;     // 0 = x-side, 1 = y-side

  __shared__ alignas(16) float red[16*RSTRIDE];   // 8.4 KB, reused x-phase then y-phase
  __shared__ alignas(16) float cLw[2][32];        // per-wave primal copy
  __shared__ alignas(16) float hLw[2][32];        // per-wave h copy
  __shared__ float pL[2][16];                     // cross-wave partials (reused per phase)

  // basis rows for this lane's timestep t = tid
  float Pr[16], Pdr[16], Pddr[16];
  #pragma unroll
  for (int q = 0; q < 4; ++q) {
    const float4 a  = *reinterpret_cast<const float4*>(P   + tid*16 + 4*q);
    const float4 bb = *reinterpret_cast<const float4*>(Pd  + tid*16 + 4*q);
    const float4 cc = *reinterpret_cast<const float4*>(Pdd + tid*16 + 4*q);
    Pr  [4*q+0]=a.x;  Pr  [4*q+1]=a.y;  Pr  [4*q+2]=a.z;  Pr  [4*q+3]=a.w;
    Pdr [4*q+0]=bb.x; Pdr [4*q+1]=bb.y; Pdr [4*q+2]=bb.z; Pdr [4*q+3]=bb.w;
    Pddr[4*q+0]=cc.x; Pddr[4*q+1]=cc.y; Pddr[4*q+2]=cc.z; Pddr[4*q+3]=cc.w;
  }

  // pre-scaled obstacle trajectories at this timestep
  float xot32[10], yot6[10];
  {
    const float tt = (float)tid * (10.0f/127.0f);
    #pragma unroll
    for (int oo = 0; oo < NOBSC; ++oo) {
      xot32[oo] = 3.2f * fmaf(vobs[b*20+oo],      tt, cobs[b*20+oo]);
      yot6 [oo] = 6.0f * fmaf(vobs[b*20+10+oo],   tt, cobs[b*20+10+oo]);
    }
  }
  const float yub = yub_g[b], ylb = ylb_g[b];

  // lambda carries: every lane redundantly tracks component (lane&15) of each side
  float lamx = lamx_g[b*16 + r16];
  float lamy = lamy_g[b*16 + r16];

  // per-lane solve-row setup: const term, initial c (row rr, side)
  float constv, myc;
  {
    float beq[9];
    const float vi  = init_state[b*4+2];
    const float psi = init_state[b*4+3];
    if (side == 0) {
      beq[0] = init_state[b*4+0];
      beq[1] = vi * cosf(psi);
      beq[2] = 0.f;
      beq[3] = fin_state[b*3+0];
      #pragma unroll
      for (int i2 = 0; i2 < 4; ++i2) beq[4+i2] = cxp_g[b*4+i2];
      beq[8] = 0.f;                      // pad: multiplies in-bounds junk * 0
    } else {
      beq[0] = init_state[b*4+1];
      beq[1] = vi * sinf(psi);
      beq[2] = 0.f;
      beq[3] = fin_state[b*3+1];
      beq[4] = 0.f;
      #pragma unroll
      for (int i2 = 0; i2 < 4; ++i2) beq[5+i2] = cyp_g[b*4+i2];
    }
    const int nstr = side ? 9 : 8;
    const float* Np  = ws + (side ? WS_NY  : WS_NX ) + rr*nstr;
    const float* N0p = ws + (side ? WS_NY0 : WS_NX0) + rr*nstr;
    float cv = 0.f, c0 = 0.f;
    #pragma unroll
    for (int mm = 0; mm < 9; ++mm) {     // x-side mm=8 reads next row * 0 (in-bounds)
      const float bm = beq[mm];
      cv = fmaf(Np[mm],  bm, cv);
      c0 = fmaf(N0p[mm], bm, c0);
    }
    constv = cv;
    myc    = c0;
    if (lane < 32) cLw[wv][lane] = c0;   // per-wave copy (same-wave DS ordering)
  }

  const float* Mrow  = ws + (side ? WS_MY  : WS_MX ) + rr*16;
  const float* MGrow = ws + (side ? WS_MGY : WS_MGX) + rr*16;

  #pragma unroll 1
  for (int it = 0; it < MAXIT; ++it) {
    // forward: x, xd, xdd, y, yd, ydd at this timestep (own wave's c copy)
    float x=0.f, y=0.f, xd=0.f, yd=0.f, xdd=0.f, ydd=0.f;
    #pragma unroll
    for (int q = 0; q < 4; ++q) {
      F4 cx4, cy4;
      cx4.v = *reinterpret_cast<const float4*>(&cLw[wv][4*q]);
      cy4.v = *reinterpret_cast<const float4*>(&cLw[wv][16 + 4*q]);
      #pragma unroll
      for (int j = 0; j < 4; ++j) {
        const int jj = 4*q + j;
        const float cc = cx4.f[j], dd = cy4.f[j];
        x   = fmaf(Pr  [jj], cc, x);   y   = fmaf(Pr  [jj], dd, y);
        xd  = fmaf(Pdr [jj], cc, xd);  yd  = fmaf(Pdr [jj], dd, yd);
        xdd = fmaf(Pddr[jj], cc, xdd); ydd = fmaf(Pddr[jj], dd, ydd);
      }
    }

    // projections (residual factors)
    const float ria = rsqrtf(fmaxf(fmaf(xdd, xdd, ydd*ydd), 1e-36f));
    const float ga1 = 1.0f - fminf(1.0f, 18.0f * ria);
    const float riv = rsqrtf(fmaxf(fmaf(xd, xd, yd*yd), 1e-36f));
    const float gv1 = 1.0f - fminf(fmaxf(1.0f, 0.1f*riv), 30.0f*riv);

    // obstacles
    float Sxp = 0.f, Syp = 0.f;
    #pragma unroll
    for (int oo = 0; oo < NOBSC; ++oo) {
      const float bw = fmaf(3.2f, x, -xot32[oo]);
      const float aw = fmaf(6.0f, y, -yot6[oo]);
      const float ri = rsqrtf(fmaxf(fmaf(bw, bw, aw*aw), 1e-36f));
      const float e  = fmaxf(fmaf(19.2f, ri, -1.0f), 0.f);
      Sxp = fmaf(e, bw, Sxp);
      Syp = fmaf(e, aw, Syp);
    }
    const float c0p = -Sxp * 0.3125f;                        // -Sx
    const float rln = fmaxf(y - yub, 0.f) - fmaxf(ylb - y, 0.f);
    const float c2p = rln - Syp * (1.0f/6.0f);               // rln - Sy
    const float c0dd = xdd * ga1, c0d = xd * gv1;
    const float c2dd = ydd * ga1, c2d = yd * gv1;

    float* col = red + tid;
    const float* rb = red + r16*RSTRIDE + (tid >> 4)*16;

    // ---- phase A: x-side residual back-projection + reduce -> hx ----
    #pragma unroll
    for (int j = 0; j < 16; ++j)
      col[j*RSTRIDE] = fmaf(c0dd, Pddr[j], fmaf(c0d, Pdr[j], c0p * Pr[j]));
    __syncthreads();                                   // bar1: red(x) ready
    {
      float s0=0.f, s1=0.f, s2=0.f, s3=0.f;
      #pragma unroll
      for (int mch = 0; mch < 4; ++mch) {
        const float4 t = *reinterpret_cast<const float4*>(rb + 4*mch);
        s0 += t.x; s1 += t.y; s2 += t.z; s3 += t.w;
      }
      float s = (s0 + s1) + (s2 + s3);
      s += __shfl_xor(s, 16);
      s += __shfl_xor(s, 32);                          // wave-local 64-col... (4 chunks)
      if (lane < 16) pL[wv][lane] = s;
      __syncthreads();                                 // bar2: partials ready; red(x) reads done
      const float Sx = s + pL[wv ^ 1][r16];            // full 128-col sum
      lamx -= Sx;
      const float hx = lamx - Sx;                      // lam_old - 2S
      if (lane < 16) hLw[wv][lane] = hx;
    }

    // ---- phase B: y-side residual back-projection + reduce -> hy ----
    #pragma unroll
    for (int j = 0; j < 16; ++j)
      col[j*RSTRIDE] = fmaf(c2dd, Pddr[j], fmaf(c2d, Pdr[j], c2p * Pr[j]));
    __syncthreads();                                   // bar3: red(y) ready
    {
      float s0=0.f, s1=0.f, s2=0.f, s3=0.f;
      #pragma unroll
      for (int mch = 0; mch < 4; ++mch) {
        const float4 t = *reinterpret_cast<const float4*>(rb + 4*mch);
        s0 += t.x; s1 += t.y; s2 += t.z; s3 += t.w;
      }
      float s = (s0 + s1) + (s2 + s3);
      s += __shfl_xor(s, 16);
      s += __shfl_xor(s, 32);
      if (lane < 16) pL[wv][lane] = s;
      __syncthreads();                                 // bar4: partials ready; red(y) reads done
      const float Sy = s + pL[wv ^ 1][r16];
      lamy -= Sy;
      const float hy = lamy - Sy;
      if (lane < 16) hLw[wv][16 + lane] = hy;
    }

    // fused solve: c' = MG*c + M*h + const   (M/MG rows from global, L1-hot)
    {
      float acc = constv;
      #pragma unroll
      for (int q = 0; q < 4; ++q) {
        F4 m4, g4, h4, c4;
        m4.v = *reinterpret_cast<const float4*>(Mrow  + 4*q);
        g4.v = *reinterpret_cast<const float4*>(MGrow + 4*q);
        h4.v = *reinterpret_cast<const float4*>(&hLw[wv][side*16 + 4*q]);
        c4.v = *reinterpret_cast<const float4*>(&cLw[wv][side*16 + 4*q]);
        #pragma unroll
        for (int j = 0; j < 4; ++j)
          acc = fmaf(g4.f[j], c4.f[j], fmaf(m4.f[j], h4.f[j], acc));
      }
      myc = acc;
      if (lane < 32) cLw[wv][lane] = acc;              // own wave's copy
    }
  }

  if (tid < 32) out[b*32 + tid] = myc;
}

extern "C" void kernel_launch(void* const* d_in, const int* in_sizes, int n_in,
                              void* d_out, int out_size, void* d_ws, size_t ws_size,
                              hipStream_t stream) {
  const float* P    = (const float*)d_in[0];
  const float* Pd   = (const float*)d_in[1];
  const float* Pdd  = (const float*)d_in[2];
  const float* init = (const float*)d_in[3];
  const float* fin  = (const float*)d_in[4];
  const float* cobs = (const float*)d_in[5];
  const float* vobs = (const float*)d_in[6];
  const float* yub  = (const float*)d_in[7];
  const float* ylb  = (const float*)d_in[8];
  const float* lamx = (const float*)d_in[9];
  const float* lamy = (const float*)d_in[10];
  const float* cxp  = (const float*)d_in[11];
  const float* cyp  = (const float*)d_in[12];
  float* ws  = (float*)d_ws;
  float* o   = (float*)d_out;

  planner_setup<<<dim3(4), dim3(64), 0, stream>>>(P, Pd, Pdd, ws);
  planner_main<<<dim3(NBATCH), dim3(128), 0, stream>>>(
      P, Pd, Pdd, init, fin, cobs, vobs, yub, ylb, lamx, lamy, cxp, cyp, ws, o);
}

// Round 7
// 240.610 us; speedup vs baseline: 1.1105x; 1.1064x over previous
//
#include <hip/hip_runtime.h>
#include <math.h>

#define NBATCH 4096
#define TNUM   128
#define NOBSC  10
#define MAXIT  30

// ws layout (floats)
#define WS_MX   0      // 16x16
#define WS_MY   256    // 16x16
#define WS_MGX  512    // 16x16  (Mx*Gx)
#define WS_MGY  768    // 16x16  (My*Gy)
#define WS_NX   1024   // 16x8
#define WS_NY   1152   // 16x9
#define WS_NX0  1296   // 16x8
#define WS_NY0  1424   // 16x9
// total 1568 floats

#define RSTRIDE 132    // padded row stride for reduction buffer (33 x 16B)

typedef float f32x2 __attribute__((ext_vector_type(2)));
union F4 { float4 v; float f[4]; };

__device__ __forceinline__ f32x2 pfma(f32x2 a, f32x2 b, f32x2 c) {
  return __builtin_elementwise_fma(a, b, c);
}

// ---------------- setup kernel: build + invert KKT matrices (fp64 GJ) -------
__global__ __launch_bounds__(64) void planner_setup(
    const float* __restrict__ P, const float* __restrict__ Pd, const float* __restrict__ Pdd,
    float* __restrict__ ws)
{
  const int mid = blockIdx.x;   // 0: (cost_sm,Ax)->Nx0  1: (cost_sm,Ay)->Ny0
                                // 2: (cost_x,Ax)->Mx,Nx,MGx 3: (cost_y,Ay)->My,Ny,MGy
  const int tid = threadIdx.x;
  __shared__ double C[16][16];
  __shared__ double G[16][16];
  __shared__ double Ae[9][16];
  __shared__ double aug[25][50];
  __shared__ int pivs;

  const bool isY = (mid & 1);
  const int  m   = isY ? 9 : 8;
  const int  n   = 16 + m;
  const int  w   = 2 * n;

  // Gram matrices + cost matrix
  for (int e = tid; e < 256; e += 64) {
    const int j = e >> 4, k = e & 15;
    double gdd = 0.0, gd = 0.0, g0 = 0.0;
    for (int t = 0; t < TNUM; ++t) {
      gdd += (double)Pdd[t*16+j] * (double)Pdd[t*16+k];
      gd  += (double)Pd [t*16+j] * (double)Pd [t*16+k];
      g0  += (double)P  [t*16+j] * (double)P  [t*16+k];
    }
    const double cs = 100.0 * (gdd + ((j == k) ? 0.1 : 0.0));   // cost_sm
    const double g  = gdd + gd + (isY ? 12.0 : 10.0) * g0;      // Gx or Gy
    G[j][k] = g;
    C[j][k] = (mid >= 2) ? (cs + g) : cs;
  }
  if (tid < 16) {
    const int j = tid;
    Ae[0][j] = (double)P  [0*16+j];
    Ae[1][j] = (double)Pd [0*16+j];
    Ae[2][j] = (double)Pdd[0*16+j];
    if (!isY) {
      Ae[3][j] = (double)Pd[127*16+j];
      for (int r = 4; r < 8; ++r) Ae[r][j] = (j == r) ? 1.0 : 0.0;
    } else {
      Ae[3][j] = (double)P [127*16+j];
      Ae[4][j] = (double)Pd[127*16+j];
      for (int r = 5; r < 9; ++r) Ae[r][j] = (j == (r-1)) ? 1.0 : 0.0;
    }
  }
  __syncthreads();

  // build augmented [KKT | I]
  for (int e = tid; e < n * w; e += 64) {
    const int r = e / w, c = e % w;
    double val;
    if (c < n) {
      if (r < 16) val = (c < 16) ? C[r][c] : Ae[c-16][r];
      else        val = (c < 16) ? Ae[r-16][c] : 0.0;
    } else {
      val = ((c - n) == r) ? 1.0 : 0.0;
    }
    aug[r][c] = val;
  }
  __syncthreads();

  // Gauss-Jordan with partial pivoting
  for (int k = 0; k < n; ++k) {
    if (tid == 0) {
      int p = k; double best = fabs(aug[k][k]);
      for (int r = k+1; r < n; ++r) { double a = fabs(aug[r][k]); if (a > best) { best = a; p = r; } }
      pivs = p;
    }
    __syncthreads();
    const int p = pivs;
    if (p != k) {
      for (int c = tid; c < w; c += 64) { double t = aug[k][c]; aug[k][c] = aug[p][c]; aug[p][c] = t; }
    }
    __syncthreads();
    const double ipiv = 1.0 / aug[k][k];
    for (int c = tid; c < w; c += 64) aug[k][c] *= ipiv;
    __syncthreads();
    for (int r = tid; r < n; r += 64) {
      if (r != k) {
        const double f = aug[r][k];
        for (int c = k; c < w; ++c) aug[r][c] -= f * aug[k][c];
      }
    }
    __syncthreads();
  }

  // write sub-blocks of the inverse (cols n.. of aug)
  if (mid == 0) {
    for (int e = tid; e < 16*8; e += 64) ws[WS_NX0 + e] = (float)aug[e >> 3][n + 16 + (e & 7)];
  } else if (mid == 1) {
    for (int e = tid; e < 16*9; e += 64) ws[WS_NY0 + e] = (float)aug[e / 9][n + 16 + (e % 9)];
  } else if (mid == 2) {
    for (int e = tid; e < 256;  e += 64) ws[WS_MX + e] = (float)aug[e >> 4][n + (e & 15)];
    for (int e = tid; e < 16*8; e += 64) ws[WS_NX + e] = (float)aug[e >> 3][n + 16 + (e & 7)];
  } else {
    for (int e = tid; e < 256;  e += 64) ws[WS_MY + e] = (float)aug[e >> 4][n + (e & 15)];
    for (int e = tid; e < 16*9; e += 64) ws[WS_NY + e] = (float)aug[e / 9][n + 16 + (e % 9)];
  }

  // MG = M * G  (fp64), for the fused per-iteration solve
  if (mid >= 2) {
    for (int e = tid; e < 256; e += 64) {
      const int j = e >> 4, k = e & 15;
      double s = 0.0;
      for (int mm = 0; mm < 16; ++mm) s += aug[j][n + mm] * G[mm][k];
      ws[(mid == 2 ? WS_MGX : WS_MGY) + e] = (float)s;
    }
  }
}

// ---------------- main kernel: 128 threads (2 waves) per batch element ------
__global__ __launch_bounds__(128, 2) void planner_main(
    const float* __restrict__ P, const float* __restrict__ Pd, const float* __restrict__ Pdd,
    const float* __restrict__ init_state, const float* __restrict__ fin_state,
    const float* __restrict__ cobs, const float* __restrict__ vobs,
    const float* __restrict__ yub_g, const float* __restrict__ ylb_g,
    const float* __restrict__ lamx_g, const float* __restrict__ lamy_g,
    const float* __restrict__ cxp_g, const float* __restrict__ cyp_g,
    const float* __restrict__ ws, float* __restrict__ out)
{
  const int b    = blockIdx.x;
  const int tid  = threadIdx.x;
  const int lane = tid & 63;
  const int wv   = tid >> 6;
  const int r32  = lane & 31;          // reduction row owned (dup over lane>=32)
  const int rr   = tid & 15;           // solve row
  const int side = (tid >> 4) & 1;     // 0 = x-side, 1 = y-side

  __shared__ alignas(16) float red[32*RSTRIDE];   // padded [o][t]
  __shared__ alignas(16) float cLw[2][32];        // per-wave primal copy (solve only)
  __shared__ alignas(16) float hLw[2][32];        // per-wave h copy (solve only)
  __shared__ float pL[2][32];                     // cross-wave partials

  // basis rows for this lane's timestep t = tid, packed as j-pairs
  f32x2 Pr2[8], Pdr2[8], Pddr2[8];
  #pragma unroll
  for (int q = 0; q < 4; ++q) {
    F4 a, bb, cc;
    a.v  = *reinterpret_cast<const float4*>(P   + tid*16 + 4*q);
    bb.v = *reinterpret_cast<const float4*>(Pd  + tid*16 + 4*q);
    cc.v = *reinterpret_cast<const float4*>(Pdd + tid*16 + 4*q);
    Pr2  [2*q+0] = f32x2{a.f[0],  a.f[1]};  Pr2  [2*q+1] = f32x2{a.f[2],  a.f[3]};
    Pdr2 [2*q+0] = f32x2{bb.f[0], bb.f[1]}; Pdr2 [2*q+1] = f32x2{bb.f[2], bb.f[3]};
    Pddr2[2*q+0] = f32x2{cc.f[0], cc.f[1]}; Pddr2[2*q+1] = f32x2{cc.f[2], cc.f[3]};
  }

  // pre-scaled obstacle trajectories at this timestep, packed as obstacle-pairs
  f32x2 xot2[5], yot2[5];
  {
    const float tt = (float)tid * (10.0f/127.0f);
    #pragma unroll
    for (int o5 = 0; o5 < 5; ++o5) {
      const int o = 2*o5;
      xot2[o5] = f32x2{3.2f * fmaf(vobs[b*20+o],      tt, cobs[b*20+o]),
                       3.2f * fmaf(vobs[b*20+o+1],    tt, cobs[b*20+o+1])};
      yot2[o5] = f32x2{6.0f * fmaf(vobs[b*20+10+o],   tt, cobs[b*20+10+o]),
                       6.0f * fmaf(vobs[b*20+11+o],   tt, cobs[b*20+11+o])};
    }
  }
  const float yub = yub_g[b], ylb = ylb_g[b];

  // lambda carry for this lane's reduction row r32 (x rows 0-15, y rows 16-31)
  float lam = (r32 < 16) ? lamx_g[b*16 + r32] : lamy_g[b*16 + (r32 - 16)];

  // per-lane solve-row setup: const term, initial c (row rr, side)
  float constv, myc;
  {
    float beq[9];
    const float vi  = init_state[b*4+2];
    const float psi = init_state[b*4+3];
    if (side == 0) {
      beq[0] = init_state[b*4+0];
      beq[1] = vi * cosf(psi);
      beq[2] = 0.f;
      beq[3] = fin_state[b*3+0];
      #pragma unroll
      for (int i2 = 0; i2 < 4; ++i2) beq[4+i2] = cxp_g[b*4+i2];
      beq[8] = 0.f;                      // pad: multiplies in-bounds junk * 0
    } else {
      beq[0] = init_state[b*4+1];
      beq[1] = vi * sinf(psi);
      beq[2] = 0.f;
      beq[3] = fin_state[b*3+1];
      beq[4] = 0.f;
      #pragma unroll
      for (int i2 = 0; i2 < 4; ++i2) beq[5+i2] = cyp_g[b*4+i2];
    }
    const int nstr = side ? 9 : 8;
    const float* Np  = ws + (side ? WS_NY  : WS_NX ) + rr*nstr;
    const float* N0p = ws + (side ? WS_NY0 : WS_NX0) + rr*nstr;
    float cv = 0.f, c0 = 0.f;
    #pragma unroll
    for (int mm = 0; mm < 9; ++mm) {     // x-side mm=8 reads next row * 0 (in-bounds)
      const float bm = beq[mm];
      cv = fmaf(Np[mm],  bm, cv);
      c0 = fmaf(N0p[mm], bm, c0);
    }
    constv = cv;
    myc    = c0;
    if (lane < 32) cLw[wv][lane] = c0;   // per-wave copy (same-wave DS ordering)
  }

  const float* Mrow  = ws + (side ? WS_MY  : WS_MX ) + rr*16;
  const float* MGrow = ws + (side ? WS_MGY : WS_MGX) + rr*16;

  #pragma unroll 1
  for (int it = 0; it < MAXIT; ++it) {
    // forward matvec (packed pairs over j): x, xd, xdd, y, yd, ydd
    f32x2 xv{}, yv{}, xdv{}, ydv{}, xddv{}, yddv{};
    #pragma unroll
    for (int q = 0; q < 4; ++q) {
      F4 cx4, cy4;
      cx4.v = *reinterpret_cast<const float4*>(&cLw[wv][4*q]);
      cy4.v = *reinterpret_cast<const float4*>(&cLw[wv][16 + 4*q]);
      const f32x2 c01 = f32x2{cx4.f[0], cx4.f[1]}, c23 = f32x2{cx4.f[2], cx4.f[3]};
      const f32x2 d01 = f32x2{cy4.f[0], cy4.f[1]}, d23 = f32x2{cy4.f[2], cy4.f[3]};
      xv   = pfma(Pr2  [2*q], c01, xv);   xv   = pfma(Pr2  [2*q+1], c23, xv);
      yv   = pfma(Pr2  [2*q], d01, yv);   yv   = pfma(Pr2  [2*q+1], d23, yv);
      xdv  = pfma(Pdr2 [2*q], c01, xdv);  xdv  = pfma(Pdr2 [2*q+1], c23, xdv);
      ydv  = pfma(Pdr2 [2*q], d01, ydv);  ydv  = pfma(Pdr2 [2*q+1], d23, ydv);
      xddv = pfma(Pddr2[2*q], c01, xddv); xddv = pfma(Pddr2[2*q+1], c23, xddv);
      yddv = pfma(Pddr2[2*q], d01, yddv); yddv = pfma(Pddr2[2*q+1], d23, yddv);
    }
    const float x   = xv.x   + xv.y,   y   = yv.x   + yv.y;
    const float xd  = xdv.x  + xdv.y,  yd  = ydv.x  + ydv.y;
    const float xdd = xddv.x + xddv.y, ydd = yddv.x + yddv.y;

    // projections (residual factors)
    const float ria = rsqrtf(fmaxf(fmaf(xdd, xdd, ydd*ydd), 1e-36f));
    const float ga1 = 1.0f - fminf(1.0f, 18.0f * ria);
    const float riv = rsqrtf(fmaxf(fmaf(xd, xd, yd*yd), 1e-36f));
    const float gv1 = 1.0f - fminf(fmaxf(1.0f, 0.1f*riv), 30.0f*riv);

    // obstacles, processed as pairs
    f32x2 Sx2{}, Sy2{};
    {
      const float t32 = 3.2f * x, t6 = 6.0f * y;
      const f32x2 xbb = f32x2{t32, t32}, ybb = f32x2{t6, t6};
      #pragma unroll
      for (int o5 = 0; o5 < 5; ++o5) {
        const f32x2 bw = xbb - xot2[o5];
        const f32x2 aw = ybb - yot2[o5];
        f32x2 r2 = pfma(bw, bw, aw*aw);
        const float e0 = fmaxf(fmaf(19.2f, rsqrtf(fmaxf(r2.x, 1e-36f)), -1.0f), 0.f);
        const float e1 = fmaxf(fmaf(19.2f, rsqrtf(fmaxf(r2.y, 1e-36f)), -1.0f), 0.f);
        const f32x2 ee = f32x2{e0, e1};
        Sx2 = pfma(ee, bw, Sx2);
        Sy2 = pfma(ee, aw, Sy2);
      }
    }
    const float Sxp = Sx2.x + Sx2.y, Syp = Sy2.x + Sy2.y;
    const float c0p = -Sxp * 0.3125f;                        // -Sx
    const float rln = fmaxf(y - yub, 0.f) - fmaxf(ylb - y, 0.f);
    const float c2p = rln - Syp * (1.0f/6.0f);               // rln - Sy
    const float c0dd = xdd * ga1, c0d = xd * gv1;
    const float c2dd = ydd * ga1, c2d = yd * gv1;

    // residual back-projection straight into LDS (packed pairs over j)
    {
      const f32x2 A0 = f32x2{c0dd, c0dd}, D0 = f32x2{c0d, c0d}, Q0 = f32x2{c0p, c0p};
      const f32x2 A2 = f32x2{c2dd, c2dd}, D2 = f32x2{c2d, c2d}, Q2 = f32x2{c2p, c2p};
      float* col = red + tid;
      #pragma unroll
      for (int j2 = 0; j2 < 8; ++j2) {
        const f32x2 vx = pfma(A0, Pddr2[j2], pfma(D0, Pdr2[j2], Q0 * Pr2[j2]));
        const f32x2 vy = pfma(A2, Pddr2[j2], pfma(D2, Pdr2[j2], Q2 * Pr2[j2]));
        col[(2*j2  )*RSTRIDE] = vx.x;
        col[(2*j2+1)*RSTRIDE] = vx.y;
        col[(16+2*j2)*RSTRIDE] = vy.x;
        col[(17+2*j2)*RSTRIDE] = vy.y;
      }
    }
    __syncthreads();                                   // A: red ready

    // reduce: lane (r32, qq) sums a 32-col chunk; conflict-free via RSTRIDE
    float h;
    {
      const int qq = tid >> 5;
      const float* rb = red + r32*RSTRIDE + (qq & 1)*32 + wv*64;
      f32x2 sA{}, sB{};
      #pragma unroll
      for (int mch = 0; mch < 8; ++mch) {
        F4 t;
        t.v = *reinterpret_cast<const float4*>(rb + 4*mch);
        sA += f32x2{t.f[0], t.f[1]};
        sB += f32x2{t.f[2], t.f[3]};
      }
      const f32x2 sAB = sA + sB;
      float s = sAB.x + sAB.y;
      s += __shfl_xor(s, 32);                          // wave-local 64-col sum
      if (lane < 32) pL[wv][lane] = s;
      __syncthreads();                                 // B: partials ready

      const float S = s + pL[wv ^ 1][r32];             // full 128-col sum
      lam -= S;
      h = lam - S;                                     // lam_old - 2S
      if (lane < 32) hLw[wv][lane] = h;
    }

    // fused solve: c' = MG*c + M*h + const   (packed pairs over k)
    {
      f32x2 accv{};
      #pragma unroll
      for (int q = 0; q < 4; ++q) {
        F4 m4, g4, h4, c4;
        m4.v = *reinterpret_cast<const float4*>(Mrow  + 4*q);
        g4.v = *reinterpret_cast<const float4*>(MGrow + 4*q);
        h4.v = *reinterpret_cast<const float4*>(&hLw[wv][side*16 + 4*q]);
        c4.v = *reinterpret_cast<const float4*>(&cLw[wv][side*16 + 4*q]);
        accv = pfma(f32x2{m4.f[0], m4.f[1]}, f32x2{h4.f[0], h4.f[1]}, accv);
        accv = pfma(f32x2{g4.f[0], g4.f[1]}, f32x2{c4.f[0], c4.f[1]}, accv);
        accv = pfma(f32x2{m4.f[2], m4.f[3]}, f32x2{h4.f[2], h4.f[3]}, accv);
        accv = pfma(f32x2{g4.f[2], g4.f[3]}, f32x2{c4.f[2], c4.f[3]}, accv);
      }
      myc = constv + accv.x + accv.y;
      if (lane < 32) cLw[wv][lane] = myc;              // own wave's copy
    }
  }

  if (tid < 32) out[b*32 + tid] = myc;
}

extern "C" void kernel_launch(void* const* d_in, const int* in_sizes, int n_in,
                              void* d_out, int out_size, void* d_ws, size_t ws_size,
                              hipStream_t stream) {
  const float* P    = (const float*)d_in[0];
  const float* Pd   = (const float*)d_in[1];
  const float* Pdd  = (const float*)d_in[2];
  const float* init = (const float*)d_in[3];
  const float* fin  = (const float*)d_in[4];
  const float* cobs = (const float*)d_in[5];
  const float* vobs = (const float*)d_in[6];
  const float* yub  = (const float*)d_in[7];
  const float* ylb  = (const float*)d_in[8];
  const float* lamx = (const float*)d_in[9];
  const float* lamy = (const float*)d_in[10];
  const float* cxp  = (const float*)d_in[11];
  const float* cyp  = (const float*)d_in[12];
  float* ws  = (float*)d_ws;
  float* o   = (float*)d_out;

  planner_setup<<<dim3(4), dim3(64), 0, stream>>>(P, Pd, Pdd, ws);
  planner_main<<<dim3(NBATCH), dim3(128), 0, stream>>>(
      P, Pd, Pdd, init, fin, cobs, vobs, yub, ylb, lamx, lamy, cxp, cyp, ws, o);
}